// Round 2
// baseline (440.407 us; speedup 1.0000x reference)
//
#include <hip/hip_runtime.h>

// ---------------------------------------------------------------- constants
#define T_N   262144
#define D_IN  128
#define H_HID 256
#define A_DIM 8
#define GAMMA 0.99f
#define EPS_C 0.2f
#define C_GL  0.9405f                 // GAMMA*LMBD
#define HALF_LOG_2PI 0.9189385332f

typedef __attribute__((ext_vector_type(8))) short short8;
typedef __attribute__((ext_vector_type(4))) float f32x4;

__device__ __forceinline__ unsigned short f2bf(float f) {
  unsigned int u = __float_as_uint(f);
  u += 0x7FFFu + ((u >> 16) & 1u);          // RNE
  return (unsigned short)(u >> 16);
}
__device__ __forceinline__ float fast_tanh(float x) {
  x = fminf(10.f, fmaxf(-10.f, x));
  float e = __expf(2.f * x);
  return 1.f - 2.f * __builtin_amdgcn_rcpf(e + 1.f);
}

// ---------------------------------------------------------------- prep:
// Wc1T/W1T: [H][D] bf16 (transposed, n-major) for B-fragments.
// H1: [16][256] bf16 actor head weights (rows0-7 = Wmu^T, 8-15 = Wlv^T)
__global__ __launch_bounds__(256) void k_prep(
    const float* __restrict__ Wc1, const float* __restrict__ W1,
    const float* __restrict__ Wmu, const float* __restrict__ Wlv,
    unsigned short* __restrict__ Wc1T, unsigned short* __restrict__ W1T,
    unsigned short* __restrict__ H1) {
  int i = blockIdx.x * 256 + threadIdx.x;
  if (i < 32768) {
    int n = i >> 7, k = i & 127;
    Wc1T[i] = f2bf(Wc1[k * 256 + n]);
  } else if (i < 65536) {
    int j = i - 32768; int n = j >> 7, k = j & 127;
    W1T[j] = f2bf(W1[k * 256 + n]);
  } else if (i < 69632) {
    int j = i - 65536; int h = j >> 8, n = j & 255;
    H1[j] = (h < 8) ? f2bf(Wmu[n * 8 + h]) : f2bf(Wlv[n * 8 + (h - 8)]);
  }
}

// ---------------------------------------------------------------- critic:
// grid (T/64, 2). job 0: v0=critic(state), job 1: v1=critic(next).
// 64 rows/block, 4 waves; wave w owns H-cols [w*64, w*64+64).
// Head (1 col) done via fp32 VALU dot from acc regs + shfl reduce — no sh_h.
__global__ __launch_bounds__(256, 4) void k_critic(
    const float* __restrict__ state, const float* __restrict__ next_state,
    const unsigned short* __restrict__ Wc1T,
    const float* __restrict__ bc1, const float* __restrict__ Wc2,
    const float* __restrict__ bc2,
    float* __restrict__ v0out, float* __restrict__ v1out) {
  const int job = blockIdx.y;
  const int r0  = blockIdx.x * 64;
  const int tid = threadIdx.x;
  const int lane = tid & 63;
  const int wv   = tid >> 6;
  const int c    = lane & 15;
  const int quad = lane >> 4;

  __shared__ unsigned short sh_x[64 * 136];    // X tile bf16, stride 136
  __shared__ float sh_v[64 * 4];               // per-wave partial v

  const float* X = job ? next_state : state;
  float* out = job ? v1out : v0out;

  // ---- stage X tile: 64 rows x 128 f32 -> bf16 LDS
  {
    const float4* Xv = (const float4*)(X + r0 * D_IN);
#pragma unroll
    for (int it = 0; it < 8; ++it) {
      int f4 = tid + it * 256;
      int row = f4 >> 5, c4 = f4 & 31;
      float4 v = Xv[f4];
      ushort4 u;
      u.x = f2bf(v.x); u.y = f2bf(v.y); u.z = f2bf(v.z); u.w = f2bf(v.w);
      *(ushort4*)(&sh_x[row * 136 + c4 * 4]) = u;
    }
  }

  // ---- preload B fragments (K=128 for this wave's 64 cols), bias, Wc2
  short8 bfrag[4][4];
  float bias_c[4], wc2_c[4];
#pragma unroll
  for (int ct = 0; ct < 4; ++ct) {
    int n = wv * 64 + ct * 16 + c;
    bias_c[ct] = bc1[n];
    wc2_c[ct]  = Wc2[n];
#pragma unroll
    for (int ki = 0; ki < 4; ++ki)
      bfrag[ct][ki] = *(const short8*)(Wc1T + n * 128 + ki * 32 + quad * 8);
  }
  __syncthreads();

  // ---- GEMM + fused critic head
#pragma unroll
  for (int rt = 0; rt < 4; ++rt) {
    f32x4 acc[4];
#pragma unroll
    for (int ct = 0; ct < 4; ++ct) acc[ct] = (f32x4){0.f, 0.f, 0.f, 0.f};
#pragma unroll
    for (int ki = 0; ki < 4; ++ki) {
      short8 a = *(const short8*)(&sh_x[(rt * 16 + c) * 136 + ki * 32 + quad * 8]);
#pragma unroll
      for (int ct = 0; ct < 4; ++ct)
        acc[ct] = __builtin_amdgcn_mfma_f32_16x16x32_bf16(a, bfrag[ct][ki], acc[ct], 0, 0, 0);
    }
    // D: row(sample)=rt*16+quad*4+r, col(hcol)=wv*64+ct*16+c
#pragma unroll
    for (int r = 0; r < 4; ++r) {
      float p = 0.f;
#pragma unroll
      for (int ct = 0; ct < 4; ++ct)
        p += fast_tanh(acc[ct][r] + bias_c[ct]) * wc2_c[ct];
      // reduce over 16 c-lanes (stay within quad)
      p += __shfl_xor(p, 1);
      p += __shfl_xor(p, 2);
      p += __shfl_xor(p, 4);
      p += __shfl_xor(p, 8);
      if (c == 0) sh_v[(rt * 16 + quad * 4 + r) * 4 + wv] = p;
    }
  }
  __syncthreads();
  if (tid < 64) {
    out[r0 + tid] = sh_v[tid * 4] + sh_v[tid * 4 + 1] + sh_v[tid * 4 + 2] +
                    sh_v[tid * 4 + 3] + bc2[0];
  }
}

// ---------------------------------------------------------------- actor:
// grid T/32. 32 rows/block, head GEMM (16 heads) via MFMA, split-K over wave pairs.
__global__ __launch_bounds__(256, 4) void k_actor(
    const float* __restrict__ state,
    const float* __restrict__ action, const float* __restrict__ beta_lp,
    const unsigned short* __restrict__ W1T, const unsigned short* __restrict__ H1,
    const float* __restrict__ b1, const float* __restrict__ bmu,
    const float* __restrict__ blv,
    float* __restrict__ ratio) {
  const int r0  = blockIdx.x * 32;
  const int tid = threadIdx.x;
  const int lane = tid & 63;
  const int wv   = tid >> 6;
  const int c    = lane & 15;
  const int quad = lane >> 4;

  __shared__ unsigned short sh_x[32 * 136];    // 8.7 KB
  __shared__ unsigned short sh_h[32 * 264];    // 16.9 KB, stride 528B = 33*16B
  __shared__ float sh_hb[2 * 32 * 16];         // [khalf][sample][head] 4 KB

  // ---- stage X tile: 32 rows x 128 f32 -> bf16 LDS
  {
    const float4* Xv = (const float4*)(state + r0 * D_IN);
#pragma unroll
    for (int it = 0; it < 4; ++it) {
      int f4 = tid + it * 256;
      int row = f4 >> 5, c4 = f4 & 31;
      float4 v = Xv[f4];
      ushort4 u;
      u.x = f2bf(v.x); u.y = f2bf(v.y); u.z = f2bf(v.z); u.w = f2bf(v.w);
      *(ushort4*)(&sh_x[row * 136 + c4 * 4]) = u;
    }
  }

  short8 bfrag[4][4];
  float bias_c[4];
#pragma unroll
  for (int ct = 0; ct < 4; ++ct) {
    int n = wv * 64 + ct * 16 + c;
    bias_c[ct] = b1[n];
#pragma unroll
    for (int ki = 0; ki < 4; ++ki)
      bfrag[ct][ki] = *(const short8*)(W1T + n * 128 + ki * 32 + quad * 8);
  }
  __syncthreads();

  // ---- main GEMM: 2 row-tiles of 16
#pragma unroll
  for (int rt = 0; rt < 2; ++rt) {
    f32x4 acc[4];
#pragma unroll
    for (int ct = 0; ct < 4; ++ct) acc[ct] = (f32x4){0.f, 0.f, 0.f, 0.f};
#pragma unroll
    for (int ki = 0; ki < 4; ++ki) {
      short8 a = *(const short8*)(&sh_x[(rt * 16 + c) * 136 + ki * 32 + quad * 8]);
#pragma unroll
      for (int ct = 0; ct < 4; ++ct)
        acc[ct] = __builtin_amdgcn_mfma_f32_16x16x32_bf16(a, bfrag[ct][ki], acc[ct], 0, 0, 0);
    }
#pragma unroll
    for (int ct = 0; ct < 4; ++ct) {
      int col = wv * 64 + ct * 16 + c;
#pragma unroll
      for (int r = 0; r < 4; ++r) {
        int row = rt * 16 + quad * 4 + r;
        sh_h[row * 264 + col] = f2bf(fast_tanh(acc[ct][r] + bias_c[ct]));
      }
    }
  }
  __syncthreads();

  // ---- head GEMM: D[head][sample], split-K: wave -> (sample-tile, K-half)
  {
    const int st = wv & 1;        // sample tile (16 samples)
    const int kh = wv >> 1;       // K half (128 of 256)
    f32x4 acc2 = (f32x4){0.f, 0.f, 0.f, 0.f};
#pragma unroll
    for (int kk = 0; kk < 4; ++kk) {
      int ki = kh * 4 + kk;
      short8 a2 = *(const short8*)(H1 + c * 256 + ki * 32 + quad * 8);            // A[head=c][k]
      short8 b2 = *(const short8*)(&sh_h[(st * 16 + c) * 264 + ki * 32 + quad * 8]); // B[k][sample=c]
      acc2 = __builtin_amdgcn_mfma_f32_16x16x32_bf16(a2, b2, acc2, 0, 0, 0);
    }
    // D: head=quad*4+r, sample=st*16+c
    *((f32x4*)&sh_hb[(kh * 32 + st * 16 + c) * 16 + quad * 4]) = acc2;
  }
  __syncthreads();

  // ---- tail: one (sample, action) per thread, shuffle-reduce over 8 actions
  {
    int s = tid >> 3, a = tid & 7;
    int t = r0 + s;
    float mu = sh_hb[(s)*16 + a] + sh_hb[(32 + s) * 16 + a] + bmu[a];
    float lv = sh_hb[(s)*16 + 8 + a] + sh_hb[(32 + s) * 16 + 8 + a] + blv[a];
    float ac = action[t * A_DIM + a];
    float bl = beta_lp[t * A_DIM + a];
    float d = ac - mu;
    float term = -0.5f * d * d * __expf(-lv) - 0.5f * lv - HALF_LOG_2PI - bl;
    term += __shfl_xor(term, 1);
    term += __shfl_xor(term, 2);
    term += __shfl_xor(term, 4);
    if (a == 0) ratio[t] = __expf(term);
  }
}

// ---------------------------------------------------------------- GAE, one kernel:
// 256 blocks x 1024 own elems; each block also reads 1024 lookahead
// (c^1024 ~ 5e-28 -> truncation below fp32 ulp). 8 elems/thread, local
// anchored sum + Kogge-Stone suffix scan with (sum, weight) composition.
__global__ __launch_bounds__(256) void k_gae(
    const float* __restrict__ reward, const float* __restrict__ v0,
    const float* __restrict__ v1, float* __restrict__ adv,
    float* __restrict__ accs) {
  const int j = blockIdx.x, k = threadIdx.x;
  const int base = j * 1024 + k * 8;           // spans [j*1024, j*1024+2048)
  float d[8];
  float s = 0.f, w = 1.f;
#pragma unroll
  for (int i = 0; i < 8; ++i) {
    int idx = base + i;
    float dd = 0.f;
    if (idx < T_N) dd = reward[idx] + GAMMA * v1[idx] - v0[idx];
    d[i] = dd;
    s += w * dd;
    w *= C_GL;
  }
  const float W8 = w;                           // c^8
  __shared__ float Ss[256], Sw[256];
  Ss[k] = s; Sw[k] = W8;
  __syncthreads();
  for (int dd = 1; dd < 256; dd <<= 1) {
    bool has = (k + dd) < 256;
    float ns = 0.f, nw = 0.f;
    if (has) { ns = Ss[k] + Sw[k] * Ss[k + dd]; nw = Sw[k] * Sw[k + dd]; }
    __syncthreads();
    if (has) { Ss[k] = ns; Sw[k] = nw; }
    __syncthreads();
  }
  float g = (k < 255) ? Ss[k + 1] : 0.f;
  float sa = 0.f, sq = 0.f;
  if (k < 128) {                                // own region only
#pragma unroll
    for (int i = 7; i >= 0; --i) {
      g = d[i] + C_GL * g;
      float a = g - v0[base + i];
      adv[base + i] = a;
      sa += a; sq += a * a;
    }
  }
  __syncthreads();
  Ss[k] = sa; Sw[k] = sq;
  __syncthreads();
  for (int off = 128; off > 0; off >>= 1) {
    if (k < off) { Ss[k] += Ss[k + off]; Sw[k] += Sw[k + off]; }
    __syncthreads();
  }
  if (k == 0) {
    atomicAdd(&accs[0], Ss[0]);                 // Σ adv
    atomicAdd(&accs[1], Sw[0]);                 // Σ adv² (= critic_loss)
  }
}

// ---------------------------------------------------------------- actor loss
__global__ __launch_bounds__(256) void k_loss(
    const float* __restrict__ adv, const float* __restrict__ ratio,
    float* __restrict__ accs) {
  int t = blockIdx.x * 256 + threadIdx.x;
  float sum  = accs[0];
  float mean = sum * (1.f / (float)T_N);
  float var  = (accs[1] - sum * mean) / (float)(T_N - 1);
  float inv  = 1.f / (sqrtf(var) + 1e-7f);
  float a = (adv[t] - mean) * inv;
  float r = ratio[t];
  float rc = fminf(fmaxf(r, 1.f - EPS_C), 1.f + EPS_C);
  float term = -fminf(r * a, rc * a);
  __shared__ float red[256];
  int k = threadIdx.x;
  red[k] = term;
  __syncthreads();
  for (int off = 128; off > 0; off >>= 1) {
    if (k < off) red[k] += red[k + off];
    __syncthreads();
  }
  if (k == 0) atomicAdd(&accs[2], red[0]);
}

__global__ void k_fin(const float* __restrict__ accs, float* __restrict__ out) {
  out[0] = accs[2] + accs[1];                   // actor_loss + critic_loss
}

// ---------------------------------------------------------------- launch
extern "C" void kernel_launch(void* const* d_in, const int* in_sizes, int n_in,
                              void* d_out, int out_size, void* d_ws, size_t ws_size,
                              hipStream_t stream) {
  const float* state      = (const float*)d_in[0];
  const float* next_state = (const float*)d_in[1];
  const float* action     = (const float*)d_in[2];
  const float* beta_lp    = (const float*)d_in[3];
  const float* reward     = (const float*)d_in[4];
  const float* W1   = (const float*)d_in[5];
  const float* b1   = (const float*)d_in[6];
  const float* Wmu  = (const float*)d_in[7];
  const float* bmu  = (const float*)d_in[8];
  const float* Wlv  = (const float*)d_in[9];
  const float* blv  = (const float*)d_in[10];
  const float* Wc1  = (const float*)d_in[11];
  const float* bc1  = (const float*)d_in[12];
  const float* Wc2  = (const float*)d_in[13];
  const float* bc2  = (const float*)d_in[14];

  char* ws = (char*)d_ws;
  size_t o = 0;
  unsigned short* Wc1T = (unsigned short*)(ws + o); o += 65536;
  unsigned short* W1T  = (unsigned short*)(ws + o); o += 65536;
  unsigned short* H1   = (unsigned short*)(ws + o); o += 8192;
  float* v0    = (float*)(ws + o); o += (size_t)T_N * 4;
  float* v1    = (float*)(ws + o); o += (size_t)T_N * 4;
  float* ratio = (float*)(ws + o); o += (size_t)T_N * 4;
  float* adv   = (float*)(ws + o); o += (size_t)T_N * 4;
  float* accs  = (float*)(ws + o); o += 256;

  hipMemsetAsync(accs, 0, 16, stream);

  k_prep<<<272, 256, 0, stream>>>(Wc1, W1, Wmu, Wlv, Wc1T, W1T, H1);

  dim3 gcrit(T_N / 64, 2);
  k_critic<<<gcrit, 256, 0, stream>>>(state, next_state, Wc1T, bc1, Wc2, bc2,
                                      v0, v1);
  k_actor<<<T_N / 32, 256, 0, stream>>>(state, action, beta_lp, W1T, H1,
                                        b1, bmu, blv, ratio);
  k_gae<<<256, 256, 0, stream>>>(reward, v0, v1, adv, accs);
  k_loss<<<T_N / 256, 256, 0, stream>>>(adv, ratio, accs);
  k_fin<<<1, 1, 0, stream>>>(accs, (float*)d_out);
}